// Round 3
// baseline (3744.754 us; speedup 1.0000x reference)
//
#include <hip/hip_runtime.h>

// PlayerPerformanceGNN: 2-layer GCN (32->16->8) + mean-pool + linear (8->5)
// N=1M, E=16M, G=10k.
// R2: bucket decomposition (dst>>BB), LDS accumulation, packed (dstLocal<<20)|src.
// R3 post-mortem: occupancy 41->76% and FETCH -27% moved k_conv only -4.5% ->
//   conv is NOT occupancy- or byte-bound; it is gather-pipeline serialized
//   (VALUBusy 4.4%, ~1 line in flight per wave by Little's law). Also
//   MAXB=2048 cut binscatter runs to ~4 edges -> 16B scattered writes -> +700us.
// R4 (this round):
//   - revert bucket build to BB=10 / NPB=1024 / MAXB=1024 / CHUNK=12288
//     (proven-cost binscatter, ~12-edge coalesced runs)
//   - conv gathers as v4f per lane (4 lanes/edge @F=16, 2 @F=8), unroll 8:
//     8 independent 16B gathers in flight per lane, loads batched before adds
//   - F-major LDS acc acc[f][node]: scatter-add bank = dl%32 (random, ~2-way
//     free) vs guaranteed 8-way for row-major; seed/epilogue stay v4f on the
//     global side
//   - hp = dis*(X@W) premultiply kept (no per-edge dis gather)
// R1 lesson: scattered 4B global stores/atomics over 64MB targets = disaster;
// all scattered accumulation stays in LDS.

namespace {

constexpr int F_IN = 32, F_H1 = 16, F_H2 = 8, N_CLS = 5;
constexpr int BB = 10, NPB = 1 << BB;   // nodes per bucket = 1024
constexpr int MAXB = 1024;              // bucket-table size (N <= 2^20)
constexpr int CHUNK = 12288;            // edges per binscatter block (48KB stage)

typedef float v4f __attribute__((ext_vector_type(4)));

// ---------------- dense matmuls (premultiplied by dis) ----------------

__global__ void k_mm1(const float* __restrict__ x, const float* __restrict__ W,
                      const float* __restrict__ dis, float* __restrict__ hp, int N) {
  __shared__ float w[F_IN * F_H1];
  for (int k = threadIdx.x; k < F_IN * F_H1; k += blockDim.x) w[k] = W[k];
  __syncthreads();
  int i = blockIdx.x * blockDim.x + threadIdx.x;
  if (i >= N) return;
  const v4f* xr = reinterpret_cast<const v4f*>(x + (size_t)i * F_IN);
  float acc[F_H1];
#pragma unroll
  for (int f = 0; f < F_H1; ++f) acc[f] = 0.f;
#pragma unroll
  for (int k4 = 0; k4 < F_IN / 4; ++k4) {
    v4f v = __builtin_nontemporal_load(&xr[k4]);
    float vv[4] = {v.x, v.y, v.z, v.w};
#pragma unroll
    for (int j = 0; j < 4; ++j) {
      const float* wr = &w[(k4 * 4 + j) * F_H1];
#pragma unroll
      for (int f = 0; f < F_H1; ++f) acc[f] = fmaf(vv[j], wr[f], acc[f]);
    }
  }
  float di = dis ? dis[i] : 1.f;
  v4f* hr = reinterpret_cast<v4f*>(hp + (size_t)i * F_H1);
#pragma unroll
  for (int q = 0; q < F_H1 / 4; ++q) {
    v4f r;
    r.x = di * acc[q * 4];
    r.y = di * acc[q * 4 + 1];
    r.z = di * acc[q * 4 + 2];
    r.w = di * acc[q * 4 + 3];
    hr[q] = r;
  }
}

__global__ void k_mm2(const float* __restrict__ in, const float* __restrict__ W,
                      const float* __restrict__ dis, float* __restrict__ hp, int N) {
  __shared__ float w[F_H1 * F_H2];
  for (int k = threadIdx.x; k < F_H1 * F_H2; k += blockDim.x) w[k] = W[k];
  __syncthreads();
  int i = blockIdx.x * blockDim.x + threadIdx.x;
  if (i >= N) return;
  const v4f* xr = reinterpret_cast<const v4f*>(in + (size_t)i * F_H1);
  float acc[F_H2];
#pragma unroll
  for (int f = 0; f < F_H2; ++f) acc[f] = 0.f;
#pragma unroll
  for (int k4 = 0; k4 < F_H1 / 4; ++k4) {
    v4f v = __builtin_nontemporal_load(&xr[k4]);
    float vv[4] = {v.x, v.y, v.z, v.w};
#pragma unroll
    for (int j = 0; j < 4; ++j) {
      const float* wr = &w[(k4 * 4 + j) * F_H2];
#pragma unroll
      for (int f = 0; f < F_H2; ++f) acc[f] = fmaf(vv[j], wr[f], acc[f]);
    }
  }
  float di = dis ? dis[i] : 1.f;
  v4f* hr = reinterpret_cast<v4f*>(hp + (size_t)i * F_H2);
#pragma unroll
  for (int q = 0; q < F_H2 / 4; ++q) {
    v4f r;
    r.x = di * acc[q * 4];
    r.y = di * acc[q * 4 + 1];
    r.z = di * acc[q * 4 + 2];
    r.w = di * acc[q * 4 + 3];
    hr[q] = r;
  }
}

__global__ void k_final(const float* __restrict__ pooled, const float* __restrict__ cnts,
                        const float* __restrict__ Wl, const float* __restrict__ bl,
                        float* __restrict__ out, int total) {
  int gid = blockIdx.x * blockDim.x + threadIdx.x;
  if (gid >= total) return;
  int g = gid / N_CLS, c = gid % N_CLS;
  float s = 0.f;
#pragma unroll
  for (int f = 0; f < F_H2; ++f) s += pooled[g * F_H2 + f] * Wl[f * N_CLS + c];
  out[gid] = s / fmaxf(cnts[g], 1.f) + bl[c];
}

// ---------------- bucket build ----------------

__global__ void k_hist(const int* __restrict__ dst, int* __restrict__ bcnt,
                       int E, int nbuck) {
  __shared__ int h[MAXB];
  for (int i = threadIdx.x; i < MAXB; i += blockDim.x) h[i] = 0;
  __syncthreads();
  for (int e = blockIdx.x * blockDim.x + threadIdx.x; e < E;
       e += gridDim.x * blockDim.x)
    atomicAdd(&h[__builtin_nontemporal_load(&dst[e]) >> BB], 1);
  __syncthreads();
  for (int i = threadIdx.x; i < nbuck; i += blockDim.x)
    if (h[i]) atomicAdd(&bcnt[i], h[i]);
}

// single block, MAXB threads: exclusive scan bcnt -> bbase (+copy to bcur)
__global__ void k_bscan(const int* __restrict__ bcnt, int* __restrict__ bbase,
                        int* __restrict__ bcur, int nbuck, int E) {
  __shared__ int s[MAXB];
  int t = threadIdx.x;
  int v = (t < nbuck) ? bcnt[t] : 0;
  s[t] = v;
  __syncthreads();
  for (int off = 1; off < MAXB; off <<= 1) {
    int x = (t >= off) ? s[t - off] : 0;
    __syncthreads();
    s[t] += x;
    __syncthreads();
  }
  int ex = s[t] - v;
  if (t < nbuck) { bbase[t] = ex; bcur[t] = ex; }
  if (t == 0) bbase[nbuck] = E;
}

// LDS-staged binned scatter: packed[pos] = (dstLocal<<20)|src, grouped by bucket
__global__ __launch_bounds__(256)
void k_binscatter(const int* __restrict__ dst, const int* __restrict__ src,
                  int* __restrict__ bcur, int* __restrict__ packed, int E) {
  __shared__ int hist[MAXB];       // chunk counts; rewritten as global base
  __shared__ int sbase[MAXB];      // exclusive scan of chunk counts
  __shared__ int lcur[MAXB];       // local cursor
  __shared__ int stg[CHUNK];       // staged packed edges, bucket order
  __shared__ int stmp[256];
  int t = threadIdx.x;
  int c0 = blockIdx.x * CHUNK;
  int n = min(CHUNK, E - c0);
  for (int i = t; i < MAXB; i += 256) hist[i] = 0;
  __syncthreads();
  for (int j = t; j < n; j += 256)
    atomicAdd(&hist[__builtin_nontemporal_load(&dst[c0 + j]) >> BB], 1);
  __syncthreads();
  // exclusive scan (4 entries/thread)
  int v[4], sum = 0;
  int b4 = t * 4;
#pragma unroll
  for (int k = 0; k < 4; ++k) { v[k] = hist[b4 + k]; sum += v[k]; }
  stmp[t] = sum;
  __syncthreads();
  for (int off = 1; off < 256; off <<= 1) {
    int x = (t >= off) ? stmp[t - off] : 0;
    __syncthreads();
    stmp[t] += x;
    __syncthreads();
  }
  int run = stmp[t] - sum;
#pragma unroll
  for (int k = 0; k < 4; ++k) { sbase[b4 + k] = run; lcur[b4 + k] = run; run += v[k]; }
  __syncthreads();
  // reserve one contiguous global range per (block,bucket); hist becomes gbase
  for (int i = t; i < MAXB; i += 256) {
    int c = hist[i];
    if (c) hist[i] = atomicAdd(&bcur[i], c);
  }
  __syncthreads();
  // stage chunk edges in bucket order
  for (int j = t; j < n; j += 256) {
    int d = __builtin_nontemporal_load(&dst[c0 + j]);
    int s = __builtin_nontemporal_load(&src[c0 + j]);
    int b = d >> BB;
    int p = atomicAdd(&lcur[b], 1);
    stg[p] = ((d & (NPB - 1)) << 20) | s;
  }
  __syncthreads();
  // write out: consecutive j in same bucket -> coalesced runs
  for (int j = t; j < n; j += 256) {
    int lo = 0, hi = MAXB - 1;
    while (lo < hi) {  // max b with sbase[b] <= j
      int mid = (lo + hi + 1) >> 1;
      if (sbase[mid] <= j) lo = mid; else hi = mid - 1;
    }
    packed[hist[lo] + (j - sbase[lo])] = stg[j];
  }
}

// per-bucket degree count -> dis = rsqrt(deg+1)
__global__ void k_dis_b(const int* __restrict__ bbase, const int* __restrict__ packed,
                        float* __restrict__ dis, int N) {
  __shared__ int cnt[NPB];
  int t = threadIdx.x;
  for (int i = t; i < NPB; i += blockDim.x) cnt[i] = 0;
  __syncthreads();
  int b = blockIdx.x;
  int beg = bbase[b], end = bbase[b + 1];
  for (int e = beg + t; e < end; e += blockDim.x)
    atomicAdd(&cnt[__builtin_nontemporal_load(&packed[e]) >> 20], 1);
  __syncthreads();
  int node0 = b << BB;
  for (int i = t; i < NPB; i += blockDim.x) {
    int node = node0 + i;
    if (node < N) dis[node] = rsqrtf((float)cnt[i] + 1.0f);
  }
}

// ---------------- bucketed conv (F-major LDS accumulate, v4f gathers) -------
// hp = dis .* (X W);  out_i = relu( dis_i * (sum_{j->i} hp_j + hp_i) + b )
// acc layout: acc[f * NPB + nodeLocal]  (scatter-add bank = node%32, random)

template <int F, int U>
__global__ __launch_bounds__(512)
void k_conv(const int* __restrict__ bbase, const int* __restrict__ packed,
            const float* __restrict__ dis, const float* __restrict__ hp,
            const float* __restrict__ bias, float* __restrict__ out, int N) {
  constexpr int RPE = F / 4;        // v4f segments per row (4 for F=16)
  constexpr int EPI = 512 / RPE;    // edges per block-iteration
  __shared__ float acc[F * NPB];    // F=16: 64KB -> 2 blocks/CU
  int t = threadIdx.x;
  int b = blockIdx.x;
  int node0 = b << BB;
  // seed acc with self contribution hp_i (v4f global read, transposed LDS write)
  for (int idx = t; idx < NPB * RPE; idx += 512) {
    int node = idx / RPE, f4 = idx % RPE;
    v4f v = {0.f, 0.f, 0.f, 0.f};
    if (node0 + node < N)
      v = *reinterpret_cast<const v4f*>(hp + (size_t)node0 * F + (size_t)idx * 4);
#pragma unroll
    for (int k = 0; k < 4; ++k) acc[(f4 * 4 + k) * NPB + node] = v[k];
  }
  __syncthreads();
  int beg = bbase[b], end = bbase[b + 1];
  int f4 = t % RPE, eg = t / RPE;
  int fb = f4 * 4;
  for (int e = beg + eg; e < end; e += U * EPI) {
    int pe[U]; bool ok[U];
#pragma unroll
    for (int u = 0; u < U; ++u) {
      int ee = e + u * EPI;
      ok[u] = ee < end;
      pe[u] = __builtin_nontemporal_load(&packed[ok[u] ? ee : beg]);
    }
    v4f hv[U];
#pragma unroll
    for (int u = 0; u < U; ++u) {
      int s = pe[u] & 0xFFFFF;
      hv[u] = *reinterpret_cast<const v4f*>(hp + (size_t)s * F + fb);
    }
#pragma unroll
    for (int u = 0; u < U; ++u) {
      int dl = pe[u] >> 20;
      if (ok[u]) {
#pragma unroll
        for (int k = 0; k < 4; ++k)
          atomicAdd(&acc[(fb + k) * NPB + dl], hv[u][k]);
      }
    }
  }
  __syncthreads();
  // epilogue: out = relu(dis_i * acc + b), streamed (nt) v4f
  for (int idx = t; idx < NPB * RPE; idx += 512) {
    int node = idx / RPE, f4o = idx % RPE;
    int g = node0 + node;
    if (g >= N) continue;
    float di = dis[g];
    v4f r;
#pragma unroll
    for (int k = 0; k < 4; ++k)
      r[k] = fmaxf(fmaf(di, acc[(f4o * 4 + k) * NPB + node], bias[f4o * 4 + k]), 0.f);
    __builtin_nontemporal_store(
        r, reinterpret_cast<v4f*>(out + (size_t)node0 * F + (size_t)idx * 4));
  }
}

// conv2 + mean-pool epilogue (no h_out write)
template <int U>
__global__ __launch_bounds__(512)
void k_conv_pool(const int* __restrict__ bbase, const int* __restrict__ packed,
                 const float* __restrict__ dis, const float* __restrict__ hp,
                 const float* __restrict__ bias, const int* __restrict__ batch,
                 float* __restrict__ pooled, float* __restrict__ cnts, int N) {
  constexpr int F = F_H2;
  constexpr int RPE = F / 4;        // 2
  constexpr int EPI = 512 / RPE;    // 256
  __shared__ float acc[F * NPB];    // 32KB
  int t = threadIdx.x;
  int b = blockIdx.x;
  int node0 = b << BB;
  for (int idx = t; idx < NPB * RPE; idx += 512) {
    int node = idx / RPE, f4 = idx % RPE;
    v4f v = {0.f, 0.f, 0.f, 0.f};
    if (node0 + node < N)
      v = *reinterpret_cast<const v4f*>(hp + (size_t)node0 * F + (size_t)idx * 4);
#pragma unroll
    for (int k = 0; k < 4; ++k) acc[(f4 * 4 + k) * NPB + node] = v[k];
  }
  __syncthreads();
  int beg = bbase[b], end = bbase[b + 1];
  int f4 = t % RPE, eg = t / RPE;
  int fb = f4 * 4;
  for (int e = beg + eg; e < end; e += U * EPI) {
    int pe[U]; bool ok[U];
#pragma unroll
    for (int u = 0; u < U; ++u) {
      int ee = e + u * EPI;
      ok[u] = ee < end;
      pe[u] = __builtin_nontemporal_load(&packed[ok[u] ? ee : beg]);
    }
    v4f hv[U];
#pragma unroll
    for (int u = 0; u < U; ++u) {
      int s = pe[u] & 0xFFFFF;
      hv[u] = *reinterpret_cast<const v4f*>(hp + (size_t)s * F + fb);
    }
#pragma unroll
    for (int u = 0; u < U; ++u) {
      int dl = pe[u] >> 20;
      if (ok[u]) {
#pragma unroll
        for (int k = 0; k < 4; ++k)
          atomicAdd(&acc[(fb + k) * NPB + dl], hv[u][k]);
      }
    }
  }
  __syncthreads();
  for (int idx = t; idx < NPB * RPE; idx += 512) {
    int node = idx / RPE, f4o = idx % RPE;
    int gn = node0 + node;
    if (gn >= N) continue;
    float di = dis[gn];
    int g = batch[gn];
#pragma unroll
    for (int k = 0; k < 4; ++k) {
      float v = fmaxf(fmaf(di, acc[(f4o * 4 + k) * NPB + node], bias[f4o * 4 + k]), 0.f);
      atomicAdd(&pooled[g * F_H2 + f4o * 4 + k], v);
    }
    if (f4o == 0) atomicAdd(&cnts[g], 1.0f);
  }
}

// ---------------- fallback (round-0 scatter atomics) ----------------

__global__ void k_deg(const int* __restrict__ dst, float* __restrict__ deg, int E) {
  int e = blockIdx.x * blockDim.x + threadIdx.x;
  if (e < E) atomicAdd(&deg[dst[e]], 1.0f);
}
__global__ void k_dis(float* __restrict__ d, int N) {
  int i = blockIdx.x * blockDim.x + threadIdx.x;
  if (i < N) d[i] = rsqrtf(d[i] + 1.0f);
}
template <int F>
__global__ void k_edge(const int* __restrict__ src, const int* __restrict__ dst,
                       const float* __restrict__ dis, const float* __restrict__ h,
                       float* __restrict__ agg, int total) {
  int gid = blockIdx.x * blockDim.x + threadIdx.x;
  if (gid >= total) return;
  int e = gid / F, f = gid % F;
  int s = src[e], d = dst[e];
  atomicAdd(&agg[d * F + f], h[s * F + f] * dis[s] * dis[d]);
}
template <int F>
__global__ void k_combine(const float* __restrict__ h, const float* __restrict__ dis,
                          const float* __restrict__ b, float* __restrict__ agg, int total) {
  int gid = blockIdx.x * blockDim.x + threadIdx.x;
  if (gid >= total) return;
  int i = gid / F, f = gid % F;
  float di = dis[i];
  agg[gid] = fmaxf(agg[gid] + h[gid] * di * di + b[f], 0.f);
}
__global__ void k_combine_pool_fb(const float* __restrict__ h2, const float* __restrict__ agg2,
                                  const float* __restrict__ dis, const float* __restrict__ b,
                                  const int* __restrict__ batch, float* __restrict__ pooled,
                                  float* __restrict__ cnts, int total) {
  int gid = blockIdx.x * blockDim.x + threadIdx.x;
  if (gid >= total) return;
  int i = gid >> 3, f = gid & 7;
  float di = dis[i];
  float v = fmaxf(agg2[gid] + h2[gid] * di * di + b[f], 0.f);
  int g = batch[i];
  atomicAdd(&pooled[g * F_H2 + f], v);
  if (f == 0) atomicAdd(&cnts[g], 1.0f);
}

}  // namespace

extern "C" void kernel_launch(void* const* d_in, const int* in_sizes, int n_in,
                              void* d_out, int out_size, void* d_ws, size_t ws_size,
                              hipStream_t stream) {
  const float* x   = (const float*)d_in[0];
  const int* ei    = (const int*)d_in[1];
  const int* batch = (const int*)d_in[2];
  const float* W1 = (const float*)d_in[4];
  const float* b1 = (const float*)d_in[5];
  const float* W2 = (const float*)d_in[6];
  const float* b2 = (const float*)d_in[7];
  const float* Wl = (const float*)d_in[8];
  const float* bl = (const float*)d_in[9];

  const int N = in_sizes[0] / F_IN;   // 1,000,000
  const int E = in_sizes[1] / 2;      // 16,000,000
  const int G = out_size / N_CLS;     // 10,000
  const int* src  = ei;
  const int* dstp = ei + E;

  const int BLK = 256;
  const int nbuck = (N + NPB - 1) >> BB;

  size_t need = (size_t)(3 * MAXB + 8) * 4   // bcnt, bbase, bcur
              + (size_t)E * 4                // packed
              + (size_t)N * 4                // dis
              + (size_t)N * F_H1 * 4         // H (hp1, later hp2)
              + (size_t)N * F_H1 * 4         // O (out1)
              + (size_t)G * (F_H2 + 1) * 4 + 1024;

  if (N <= (1 << 20) && nbuck <= MAXB && ws_size >= need) {
    char* p = (char*)d_ws;
    int*   bcnt   = (int*)p;    p += (size_t)MAXB * 4;
    int*   bbase  = (int*)p;    p += (size_t)(MAXB + 4) * 4;
    int*   bcur   = (int*)p;    p += (size_t)MAXB * 4;
    int*   packed = (int*)p;    p += (size_t)E * 4;
    float* dis    = (float*)p;  p += (size_t)N * 4;
    float* H      = (float*)p;  p += (size_t)N * F_H1 * 4;
    float* O      = (float*)p;  p += (size_t)N * F_H1 * 4;
    float* pooled = (float*)p;  p += (size_t)G * F_H2 * 4;
    float* cnts   = (float*)p;

    (void)hipMemsetAsync(bcnt, 0, (size_t)MAXB * 4, stream);
    (void)hipMemsetAsync(pooled, 0, ((size_t)G * F_H2 + G) * 4, stream);

    // bucket build (dis before mm1 so the matmul can premultiply)
    k_hist<<<2048, BLK, 0, stream>>>(dstp, bcnt, E, nbuck);
    k_bscan<<<1, MAXB, 0, stream>>>(bcnt, bbase, bcur, nbuck, E);
    k_binscatter<<<(E + CHUNK - 1) / CHUNK, BLK, 0, stream>>>(dstp, src, bcur, packed, E);
    k_dis_b<<<nbuck, BLK, 0, stream>>>(bbase, packed, dis, N);

    // conv1: hp1 = dis .* (x @ W1)
    k_mm1<<<(N + BLK - 1) / BLK, BLK, 0, stream>>>(x, W1, dis, H, N);
    k_conv<F_H1, 8><<<nbuck, 512, 0, stream>>>(bbase, packed, dis, H, b1, O, N);
    // conv2: hp2 = dis .* (O @ W2)  (reuses H)
    k_mm2<<<(N + BLK - 1) / BLK, BLK, 0, stream>>>(O, W2, dis, H, N);
    k_conv_pool<8><<<nbuck, 512, 0, stream>>>(bbase, packed, dis, H, b2, batch,
                                              pooled, cnts, N);

    k_final<<<(G * N_CLS + BLK - 1) / BLK, BLK, 0, stream>>>(
        pooled, cnts, Wl, bl, (float*)d_out, G * N_CLS);
    return;
  }

  // ---------- fallback: round-0 scatter-atomic path ----------
  float* ws = (float*)d_ws;
  float* dis    = ws;
  float* A      = ws + N;
  float* B      = A + (size_t)N * F_H1;
  float* h2     = A;
  float* agg2   = A + (size_t)N * F_H2;
  float* pooled = B + (size_t)N * F_H1;
  float* cnts   = pooled + (size_t)G * F_H2;

  (void)hipMemsetAsync(dis, 0, (size_t)N * sizeof(float), stream);
  (void)hipMemsetAsync(B, 0, (size_t)N * F_H1 * sizeof(float), stream);
  (void)hipMemsetAsync(pooled, 0, ((size_t)G * F_H2 + G) * sizeof(float), stream);

  k_deg<<<(E + BLK - 1) / BLK, BLK, 0, stream>>>(dstp, dis, E);
  k_dis<<<(N + BLK - 1) / BLK, BLK, 0, stream>>>(dis, N);
  k_mm1<<<(N + BLK - 1) / BLK, BLK, 0, stream>>>(x, W1, nullptr, A, N);
  k_edge<F_H1><<<(E * F_H1 + BLK - 1) / BLK, BLK, 0, stream>>>(src, dstp, dis, A, B, E * F_H1);
  k_combine<F_H1><<<(N * F_H1 + BLK - 1) / BLK, BLK, 0, stream>>>(A, dis, b1, B, N * F_H1);
  (void)hipMemsetAsync(agg2, 0, (size_t)N * F_H2 * sizeof(float), stream);
  k_mm2<<<(N + BLK - 1) / BLK, BLK, 0, stream>>>(B, W2, nullptr, h2, N);
  k_edge<F_H2><<<(E * F_H2 + BLK - 1) / BLK, BLK, 0, stream>>>(src, dstp, dis, h2, agg2, E * F_H2);
  k_combine_pool_fb<<<(N * F_H2 + BLK - 1) / BLK, BLK, 0, stream>>>(
      h2, agg2, dis, b2, batch, pooled, cnts, N * F_H2);
  k_final<<<(G * N_CLS + BLK - 1) / BLK, BLK, 0, stream>>>(
      pooled, cnts, Wl, bl, (float*)d_out, G * N_CLS);
}

// Round 4
// 3479.485 us; speedup vs baseline: 1.0762x; 1.0762x over previous
//
#include <hip/hip_runtime.h>

// PlayerPerformanceGNN: 2-layer GCN (32->16->8) + mean-pool + linear (8->5)
// N=1M, E=16M, G=10k.
// R2: bucket decomposition (dst>>BB=10), LDS accumulation, packed (dstLocal<<20)|src.
// R3/R4 post-mortem: conv time invariant ~1365-1430us across occupancy 41->76%,
//   unroll 2->8, scalar->v4f gathers => NOT latency/MLP-bound. 16M random line
//   fetches at ~12G lines/s, FETCH/edge ~90B => every gather misses to fabric.
//   Random-access ceiling: transactions or bytes. R4's F-major acc put all F
//   atomics of an edge on ONE bank (NPB%32==0) and regressed conv_pool ~+900us.
// R5 (this round):
//   - revert convs to proven row-major acc, scalar gathers, unroll 4, NPB=1024
//   - hp stored as fp16 (premultiplied by dis in the matmuls): gather row 32B
//     (conv1) / 16B (conv2), array 32/16MB. Same transaction count, half the
//     bytes -> discriminates byte-bound vs transaction-bound; big win if bytes.
//     Also makes a 4MB slice = one XCD L2 for future L2-resident phasing.
// R1 lesson: scattered 4B global stores/atomics over 64MB targets = disaster;
// all scattered accumulation stays in LDS.

namespace {

constexpr int F_IN = 32, F_H1 = 16, F_H2 = 8, N_CLS = 5;
constexpr int BB = 10, NPB = 1 << BB;   // nodes per bucket = 1024
constexpr int MAXB = 1024;              // bucket-table size (N <= 2^20)
constexpr int CHUNK = 12288;            // edges per binscatter block (48KB stage)

typedef float v4f __attribute__((ext_vector_type(4)));
typedef _Float16 v8h __attribute__((ext_vector_type(8)));

// ---------------- dense matmuls (premultiplied by dis) ----------------
// T = _Float16 (main path, packed v8h stores) or float (fallback path)

template <typename T>
__global__ void k_mm1(const float* __restrict__ x, const float* __restrict__ W,
                      const float* __restrict__ dis, T* __restrict__ hp, int N) {
  __shared__ float w[F_IN * F_H1];
  for (int k = threadIdx.x; k < F_IN * F_H1; k += blockDim.x) w[k] = W[k];
  __syncthreads();
  int i = blockIdx.x * blockDim.x + threadIdx.x;
  if (i >= N) return;
  const v4f* xr = reinterpret_cast<const v4f*>(x + (size_t)i * F_IN);
  float acc[F_H1];
#pragma unroll
  for (int f = 0; f < F_H1; ++f) acc[f] = 0.f;
#pragma unroll
  for (int k4 = 0; k4 < F_IN / 4; ++k4) {
    v4f v = __builtin_nontemporal_load(&xr[k4]);
    float vv[4] = {v.x, v.y, v.z, v.w};
#pragma unroll
    for (int j = 0; j < 4; ++j) {
      const float* wr = &w[(k4 * 4 + j) * F_H1];
#pragma unroll
      for (int f = 0; f < F_H1; ++f) acc[f] = fmaf(vv[j], wr[f], acc[f]);
    }
  }
  float di = dis ? dis[i] : 1.f;
  if constexpr (sizeof(T) == 2) {
    v8h r0, r1;
#pragma unroll
    for (int k = 0; k < 8; ++k) {
      r0[k] = (_Float16)(di * acc[k]);
      r1[k] = (_Float16)(di * acc[8 + k]);
    }
    v8h* hr = reinterpret_cast<v8h*>((_Float16*)hp + (size_t)i * F_H1);
    hr[0] = r0;
    hr[1] = r1;
  } else {
#pragma unroll
    for (int f = 0; f < F_H1; ++f) hp[(size_t)i * F_H1 + f] = di * acc[f];
  }
}

template <typename T>
__global__ void k_mm2(const float* __restrict__ in, const float* __restrict__ W,
                      const float* __restrict__ dis, T* __restrict__ hp, int N) {
  __shared__ float w[F_H1 * F_H2];
  for (int k = threadIdx.x; k < F_H1 * F_H2; k += blockDim.x) w[k] = W[k];
  __syncthreads();
  int i = blockIdx.x * blockDim.x + threadIdx.x;
  if (i >= N) return;
  const v4f* xr = reinterpret_cast<const v4f*>(in + (size_t)i * F_H1);
  float acc[F_H2];
#pragma unroll
  for (int f = 0; f < F_H2; ++f) acc[f] = 0.f;
#pragma unroll
  for (int k4 = 0; k4 < F_H1 / 4; ++k4) {
    v4f v = __builtin_nontemporal_load(&xr[k4]);
    float vv[4] = {v.x, v.y, v.z, v.w};
#pragma unroll
    for (int j = 0; j < 4; ++j) {
      const float* wr = &w[(k4 * 4 + j) * F_H2];
#pragma unroll
      for (int f = 0; f < F_H2; ++f) acc[f] = fmaf(vv[j], wr[f], acc[f]);
    }
  }
  float di = dis ? dis[i] : 1.f;
  if constexpr (sizeof(T) == 2) {
    v8h r;
#pragma unroll
    for (int k = 0; k < 8; ++k) r[k] = (_Float16)(di * acc[k]);
    *reinterpret_cast<v8h*>((_Float16*)hp + (size_t)i * F_H2) = r;
  } else {
#pragma unroll
    for (int f = 0; f < F_H2; ++f) hp[(size_t)i * F_H2 + f] = di * acc[f];
  }
}

__global__ void k_final(const float* __restrict__ pooled, const float* __restrict__ cnts,
                        const float* __restrict__ Wl, const float* __restrict__ bl,
                        float* __restrict__ out, int total) {
  int gid = blockIdx.x * blockDim.x + threadIdx.x;
  if (gid >= total) return;
  int g = gid / N_CLS, c = gid % N_CLS;
  float s = 0.f;
#pragma unroll
  for (int f = 0; f < F_H2; ++f) s += pooled[g * F_H2 + f] * Wl[f * N_CLS + c];
  out[gid] = s / fmaxf(cnts[g], 1.f) + bl[c];
}

// ---------------- bucket build ----------------

__global__ void k_hist(const int* __restrict__ dst, int* __restrict__ bcnt,
                       int E, int nbuck) {
  __shared__ int h[MAXB];
  for (int i = threadIdx.x; i < MAXB; i += blockDim.x) h[i] = 0;
  __syncthreads();
  for (int e = blockIdx.x * blockDim.x + threadIdx.x; e < E;
       e += gridDim.x * blockDim.x)
    atomicAdd(&h[__builtin_nontemporal_load(&dst[e]) >> BB], 1);
  __syncthreads();
  for (int i = threadIdx.x; i < nbuck; i += blockDim.x)
    if (h[i]) atomicAdd(&bcnt[i], h[i]);
}

// single block, MAXB threads: exclusive scan bcnt -> bbase (+copy to bcur)
__global__ void k_bscan(const int* __restrict__ bcnt, int* __restrict__ bbase,
                        int* __restrict__ bcur, int nbuck, int E) {
  __shared__ int s[MAXB];
  int t = threadIdx.x;
  int v = (t < nbuck) ? bcnt[t] : 0;
  s[t] = v;
  __syncthreads();
  for (int off = 1; off < MAXB; off <<= 1) {
    int x = (t >= off) ? s[t - off] : 0;
    __syncthreads();
    s[t] += x;
    __syncthreads();
  }
  int ex = s[t] - v;
  if (t < nbuck) { bbase[t] = ex; bcur[t] = ex; }
  if (t == 0) bbase[nbuck] = E;
}

// LDS-staged binned scatter: packed[pos] = (dstLocal<<20)|src, grouped by bucket
__global__ __launch_bounds__(256)
void k_binscatter(const int* __restrict__ dst, const int* __restrict__ src,
                  int* __restrict__ bcur, int* __restrict__ packed, int E) {
  __shared__ int hist[MAXB];       // chunk counts; rewritten as global base
  __shared__ int sbase[MAXB];      // exclusive scan of chunk counts
  __shared__ int lcur[MAXB];       // local cursor
  __shared__ int stg[CHUNK];       // staged packed edges, bucket order
  __shared__ int stmp[256];
  int t = threadIdx.x;
  int c0 = blockIdx.x * CHUNK;
  int n = min(CHUNK, E - c0);
  for (int i = t; i < MAXB; i += 256) hist[i] = 0;
  __syncthreads();
  for (int j = t; j < n; j += 256)
    atomicAdd(&hist[__builtin_nontemporal_load(&dst[c0 + j]) >> BB], 1);
  __syncthreads();
  // exclusive scan (4 entries/thread)
  int v[4], sum = 0;
  int b4 = t * 4;
#pragma unroll
  for (int k = 0; k < 4; ++k) { v[k] = hist[b4 + k]; sum += v[k]; }
  stmp[t] = sum;
  __syncthreads();
  for (int off = 1; off < 256; off <<= 1) {
    int x = (t >= off) ? stmp[t - off] : 0;
    __syncthreads();
    stmp[t] += x;
    __syncthreads();
  }
  int run = stmp[t] - sum;
#pragma unroll
  for (int k = 0; k < 4; ++k) { sbase[b4 + k] = run; lcur[b4 + k] = run; run += v[k]; }
  __syncthreads();
  // reserve one contiguous global range per (block,bucket); hist becomes gbase
  for (int i = t; i < MAXB; i += 256) {
    int c = hist[i];
    if (c) hist[i] = atomicAdd(&bcur[i], c);
  }
  __syncthreads();
  // stage chunk edges in bucket order
  for (int j = t; j < n; j += 256) {
    int d = __builtin_nontemporal_load(&dst[c0 + j]);
    int s = __builtin_nontemporal_load(&src[c0 + j]);
    int b = d >> BB;
    int p = atomicAdd(&lcur[b], 1);
    stg[p] = ((d & (NPB - 1)) << 20) | s;
  }
  __syncthreads();
  // write out: consecutive j in same bucket -> coalesced runs
  for (int j = t; j < n; j += 256) {
    int lo = 0, hi = MAXB - 1;
    while (lo < hi) {  // max b with sbase[b] <= j
      int mid = (lo + hi + 1) >> 1;
      if (sbase[mid] <= j) lo = mid; else hi = mid - 1;
    }
    packed[hist[lo] + (j - sbase[lo])] = stg[j];
  }
}

// per-bucket degree count -> dis = rsqrt(deg+1)
__global__ void k_dis_b(const int* __restrict__ bbase, const int* __restrict__ packed,
                        float* __restrict__ dis, int N) {
  __shared__ int cnt[NPB];
  int t = threadIdx.x;
  for (int i = t; i < NPB; i += blockDim.x) cnt[i] = 0;
  __syncthreads();
  int b = blockIdx.x;
  int beg = bbase[b], end = bbase[b + 1];
  for (int e = beg + t; e < end; e += blockDim.x)
    atomicAdd(&cnt[__builtin_nontemporal_load(&packed[e]) >> 20], 1);
  __syncthreads();
  int node0 = b << BB;
  for (int i = t; i < NPB; i += blockDim.x) {
    int node = node0 + i;
    if (node < N) dis[node] = rsqrtf((float)cnt[i] + 1.0f);
  }
}

// ---------------- bucketed conv (row-major LDS acc, fp16 gathers) ----------
// hp = fp16(dis .* (X W));  out_i = relu( dis_i * (sum_{j->i} hp_j + hp_i) + b )
// (self loop: di^2 * h_i == di * hp_i, so seed acc with hp_i)

template <int F, int U>
__global__ __launch_bounds__(512)
void k_conv(const int* __restrict__ bbase, const int* __restrict__ packed,
            const float* __restrict__ dis, const _Float16* __restrict__ hp,
            const float* __restrict__ bias, float* __restrict__ out, int N) {
  constexpr int EPI = 512 / F;      // edges per block-iteration
  __shared__ float acc[NPB * F];    // F=16: 64KB -> 2 blocks/CU (proven)
  int t = threadIdx.x;
  int b = blockIdx.x;
  int node0 = b << BB;
  // seed acc with self contribution hp_i (v8h coalesced reads)
  for (int idx = t; idx < NPB * F / 8; idx += 512) {
    int node = idx / (F / 8);
    v8h v = {};
    if (node0 + node < N)
      v = *reinterpret_cast<const v8h*>(hp + (size_t)node0 * F + (size_t)idx * 8);
#pragma unroll
    for (int k = 0; k < 8; ++k) acc[idx * 8 + k] = (float)v[k];
  }
  __syncthreads();
  int beg = bbase[b], end = bbase[b + 1];
  int f = t % F, eg = t / F;
  for (int e = beg + eg; e < end; e += U * EPI) {
    int pe[U]; bool ok[U];
#pragma unroll
    for (int u = 0; u < U; ++u) {
      int ee = e + u * EPI;
      ok[u] = ee < end;
      pe[u] = __builtin_nontemporal_load(&packed[ok[u] ? ee : beg]);
    }
    float hv[U];
#pragma unroll
    for (int u = 0; u < U; ++u)
      hv[u] = (float)hp[(size_t)(pe[u] & 0xFFFFF) * F + f];
#pragma unroll
    for (int u = 0; u < U; ++u)
      if (ok[u]) atomicAdd(&acc[(pe[u] >> 20) * F + f], hv[u]);
  }
  __syncthreads();
  // epilogue: out = relu(dis_i * acc + b), streamed (nt) v4f
  for (int i4 = t; i4 < NPB * F / 4; i4 += 512) {
    int idx = i4 * 4;
    int node = node0 + idx / F;
    if (node >= N) continue;
    int ff = idx % F;
    float di = dis[node];
    v4f a = *reinterpret_cast<const v4f*>(&acc[idx]);
    v4f r;
    r.x = fmaxf(fmaf(di, a.x, bias[ff + 0]), 0.f);
    r.y = fmaxf(fmaf(di, a.y, bias[ff + 1]), 0.f);
    r.z = fmaxf(fmaf(di, a.z, bias[ff + 2]), 0.f);
    r.w = fmaxf(fmaf(di, a.w, bias[ff + 3]), 0.f);
    __builtin_nontemporal_store(
        r, reinterpret_cast<v4f*>(out + (size_t)node0 * F + idx));
  }
}

// conv2 + mean-pool epilogue (no h_out write)
template <int U>
__global__ __launch_bounds__(512)
void k_conv_pool(const int* __restrict__ bbase, const int* __restrict__ packed,
                 const float* __restrict__ dis, const _Float16* __restrict__ hp,
                 const float* __restrict__ bias, const int* __restrict__ batch,
                 float* __restrict__ pooled, float* __restrict__ cnts, int N) {
  constexpr int F = F_H2;
  constexpr int EPI = 512 / F;      // 64
  __shared__ float acc[NPB * F];    // 32KB
  int t = threadIdx.x;
  int b = blockIdx.x;
  int node0 = b << BB;
  for (int idx = t; idx < NPB; idx += 512) {  // one v8h = one row (F=8)
    int node = idx;
    v8h v = {};
    if (node0 + node < N)
      v = *reinterpret_cast<const v8h*>(hp + (size_t)node0 * F + (size_t)idx * 8);
#pragma unroll
    for (int k = 0; k < 8; ++k) acc[idx * 8 + k] = (float)v[k];
  }
  __syncthreads();
  int beg = bbase[b], end = bbase[b + 1];
  int f = t % F, eg = t / F;
  for (int e = beg + eg; e < end; e += U * EPI) {
    int pe[U]; bool ok[U];
#pragma unroll
    for (int u = 0; u < U; ++u) {
      int ee = e + u * EPI;
      ok[u] = ee < end;
      pe[u] = __builtin_nontemporal_load(&packed[ok[u] ? ee : beg]);
    }
    float hv[U];
#pragma unroll
    for (int u = 0; u < U; ++u)
      hv[u] = (float)hp[(size_t)(pe[u] & 0xFFFFF) * F + f];
#pragma unroll
    for (int u = 0; u < U; ++u)
      if (ok[u]) atomicAdd(&acc[(pe[u] >> 20) * F + f], hv[u]);
  }
  __syncthreads();
  for (int i = t; i < NPB * F; i += 512) {
    int node = node0 + i / F;
    if (node >= N) continue;
    int ff = i % F;
    float di = dis[node];
    float v = fmaxf(fmaf(di, acc[i], bias[ff]), 0.f);
    int g = batch[node];
    atomicAdd(&pooled[g * F_H2 + ff], v);
    if (ff == 0) atomicAdd(&cnts[g], 1.0f);
  }
}

// ---------------- fallback (round-0 scatter atomics, fp32) ----------------

__global__ void k_deg(const int* __restrict__ dst, float* __restrict__ deg, int E) {
  int e = blockIdx.x * blockDim.x + threadIdx.x;
  if (e < E) atomicAdd(&deg[dst[e]], 1.0f);
}
__global__ void k_dis(float* __restrict__ d, int N) {
  int i = blockIdx.x * blockDim.x + threadIdx.x;
  if (i < N) d[i] = rsqrtf(d[i] + 1.0f);
}
template <int F>
__global__ void k_edge(const int* __restrict__ src, const int* __restrict__ dst,
                       const float* __restrict__ dis, const float* __restrict__ h,
                       float* __restrict__ agg, int total) {
  int gid = blockIdx.x * blockDim.x + threadIdx.x;
  if (gid >= total) return;
  int e = gid / F, f = gid % F;
  int s = src[e], d = dst[e];
  atomicAdd(&agg[d * F + f], h[s * F + f] * dis[s] * dis[d]);
}
template <int F>
__global__ void k_combine(const float* __restrict__ h, const float* __restrict__ dis,
                          const float* __restrict__ b, float* __restrict__ agg, int total) {
  int gid = blockIdx.x * blockDim.x + threadIdx.x;
  if (gid >= total) return;
  int i = gid / F, f = gid % F;
  float di = dis[i];
  agg[gid] = fmaxf(agg[gid] + h[gid] * di * di + b[f], 0.f);
}
__global__ void k_combine_pool_fb(const float* __restrict__ h2, const float* __restrict__ agg2,
                                  const float* __restrict__ dis, const float* __restrict__ b,
                                  const int* __restrict__ batch, float* __restrict__ pooled,
                                  float* __restrict__ cnts, int total) {
  int gid = blockIdx.x * blockDim.x + threadIdx.x;
  if (gid >= total) return;
  int i = gid >> 3, f = gid & 7;
  float di = dis[i];
  float v = fmaxf(agg2[gid] + h2[gid] * di * di + b[f], 0.f);
  int g = batch[i];
  atomicAdd(&pooled[g * F_H2 + f], v);
  if (f == 0) atomicAdd(&cnts[g], 1.0f);
}

}  // namespace

extern "C" void kernel_launch(void* const* d_in, const int* in_sizes, int n_in,
                              void* d_out, int out_size, void* d_ws, size_t ws_size,
                              hipStream_t stream) {
  const float* x   = (const float*)d_in[0];
  const int* ei    = (const int*)d_in[1];
  const int* batch = (const int*)d_in[2];
  const float* W1 = (const float*)d_in[4];
  const float* b1 = (const float*)d_in[5];
  const float* W2 = (const float*)d_in[6];
  const float* b2 = (const float*)d_in[7];
  const float* Wl = (const float*)d_in[8];
  const float* bl = (const float*)d_in[9];

  const int N = in_sizes[0] / F_IN;   // 1,000,000
  const int E = in_sizes[1] / 2;      // 16,000,000
  const int G = out_size / N_CLS;     // 10,000
  const int* src  = ei;
  const int* dstp = ei + E;

  const int BLK = 256;
  const int nbuck = (N + NPB - 1) >> BB;

  size_t need = (size_t)(3 * MAXB + 8) * 4   // bcnt, bbase, bcur
              + (size_t)E * 4                // packed
              + (size_t)N * 4                // dis
              + (size_t)N * F_H1 * 2         // H16 (hp1 fp16; hp2 reuses)
              + (size_t)N * F_H1 * 4         // O (out1 fp32)
              + (size_t)G * (F_H2 + 1) * 4 + 1024;

  if (N <= (1 << 20) && nbuck <= MAXB && ws_size >= need) {
    char* p = (char*)d_ws;
    int*       bcnt   = (int*)p;       p += (size_t)MAXB * 4;
    int*       bbase  = (int*)p;       p += (size_t)(MAXB + 4) * 4;
    int*       bcur   = (int*)p;       p += (size_t)MAXB * 4;
    int*       packed = (int*)p;       p += (size_t)E * 4;
    float*     dis    = (float*)p;     p += (size_t)N * 4;
    _Float16*  H16    = (_Float16*)p;  p += (size_t)N * F_H1 * 2;
    float*     O      = (float*)p;     p += (size_t)N * F_H1 * 4;
    float*     pooled = (float*)p;     p += (size_t)G * F_H2 * 4;
    float*     cnts   = (float*)p;

    (void)hipMemsetAsync(bcnt, 0, (size_t)MAXB * 4, stream);
    (void)hipMemsetAsync(pooled, 0, ((size_t)G * F_H2 + G) * 4, stream);

    // bucket build (dis before mm1 so the matmul can premultiply)
    k_hist<<<2048, BLK, 0, stream>>>(dstp, bcnt, E, nbuck);
    k_bscan<<<1, MAXB, 0, stream>>>(bcnt, bbase, bcur, nbuck, E);
    k_binscatter<<<(E + CHUNK - 1) / CHUNK, BLK, 0, stream>>>(dstp, src, bcur, packed, E);
    k_dis_b<<<nbuck, BLK, 0, stream>>>(bbase, packed, dis, N);

    // conv1: hp1 = fp16(dis .* (x @ W1))
    k_mm1<_Float16><<<(N + BLK - 1) / BLK, BLK, 0, stream>>>(x, W1, dis, H16, N);
    k_conv<F_H1, 4><<<nbuck, 512, 0, stream>>>(bbase, packed, dis, H16, b1, O, N);
    // conv2: hp2 = fp16(dis .* (O @ W2))  (reuses H16)
    k_mm2<_Float16><<<(N + BLK - 1) / BLK, BLK, 0, stream>>>(O, W2, dis, H16, N);
    k_conv_pool<4><<<nbuck, 512, 0, stream>>>(bbase, packed, dis, H16, b2, batch,
                                              pooled, cnts, N);

    k_final<<<(G * N_CLS + BLK - 1) / BLK, BLK, 0, stream>>>(
        pooled, cnts, Wl, bl, (float*)d_out, G * N_CLS);
    return;
  }

  // ---------- fallback: round-0 scatter-atomic path (fp32) ----------
  float* ws = (float*)d_ws;
  float* dis    = ws;
  float* A      = ws + N;
  float* B      = A + (size_t)N * F_H1;
  float* h2     = A;
  float* agg2   = A + (size_t)N * F_H2;
  float* pooled = B + (size_t)N * F_H1;
  float* cnts   = pooled + (size_t)G * F_H2;

  (void)hipMemsetAsync(dis, 0, (size_t)N * sizeof(float), stream);
  (void)hipMemsetAsync(B, 0, (size_t)N * F_H1 * sizeof(float), stream);
  (void)hipMemsetAsync(pooled, 0, ((size_t)G * F_H2 + G) * sizeof(float), stream);

  k_deg<<<(E + BLK - 1) / BLK, BLK, 0, stream>>>(dstp, dis, E);
  k_dis<<<(N + BLK - 1) / BLK, BLK, 0, stream>>>(dis, N);
  k_mm1<float><<<(N + BLK - 1) / BLK, BLK, 0, stream>>>(x, W1, nullptr, A, N);
  k_edge<F_H1><<<(E * F_H1 + BLK - 1) / BLK, BLK, 0, stream>>>(src, dstp, dis, A, B, E * F_H1);
  k_combine<F_H1><<<(N * F_H1 + BLK - 1) / BLK, BLK, 0, stream>>>(A, dis, b1, B, N * F_H1);
  (void)hipMemsetAsync(agg2, 0, (size_t)N * F_H2 * sizeof(float), stream);
  k_mm2<float><<<(N + BLK - 1) / BLK, BLK, 0, stream>>>(B, W2, nullptr, h2, N);
  k_edge<F_H2><<<(E * F_H2 + BLK - 1) / BLK, BLK, 0, stream>>>(src, dstp, dis, h2, agg2, E * F_H2);
  k_combine_pool_fb<<<(N * F_H2 + BLK - 1) / BLK, BLK, 0, stream>>>(
      h2, agg2, dis, b2, batch, pooled, cnts, N * F_H2);
  k_final<<<(G * N_CLS + BLK - 1) / BLK, BLK, 0, stream>>>(
      pooled, cnts, Wl, bl, (float*)d_out, G * N_CLS);
}